// Round 1
// baseline (445.567 us; speedup 1.0000x reference)
//
#include <hip/hip_runtime.h>
#include <hip/hip_bf16.h>

#define N_NODES 50000
#define N_EDGES 600000
#define N_PAIRS 100000

typedef __attribute__((ext_vector_type(8))) short bf16x8;
typedef __attribute__((ext_vector_type(4))) float f32x4;

__device__ inline unsigned short f2b(float f) {
    unsigned u = __float_as_uint(f);
    unsigned r = u + 0x7fff + ((u >> 16) & 1);
    return (unsigned short)(r >> 16);
}
__device__ inline float b2f(unsigned short h) {
    return __uint_as_float(((unsigned)h) << 16);
}

// ---- convert x (fp32 [N][128]) into A1[:, 0:128] bf16 (ld 256) ----
__global__ void k_convert_x(const float* __restrict__ x, unsigned short* __restrict__ A1) {
    int idx = blockIdx.x * blockDim.x + threadIdx.x;   // one float4 per thread
    if (idx >= N_NODES * 32) return;
    int row = idx >> 5, c4 = (idx & 31) * 4;
    float4 v = *(const float4*)(x + row * 128 + c4);
    unsigned lo = (unsigned)f2b(v.x) | ((unsigned)f2b(v.y) << 16);
    unsigned hi = (unsigned)f2b(v.z) | ((unsigned)f2b(v.w) << 16);
    uint2 o; o.x = lo; o.y = hi;
    *(uint2*)(A1 + row * 256 + c4) = o;
}

// ---- build transposed bf16 weights ----
// WT1[n][k] (k<128 -> Ws1[k][n], else Wn1[k-128][n]) ; WT2 likewise ; WdT1/WdT2 [n][k]=Wd[k][n]
__global__ void k_prep_w(const float* __restrict__ Ws1, const float* __restrict__ Wn1,
                         const float* __restrict__ Ws2, const float* __restrict__ Wn2,
                         const float* __restrict__ Wd1, const float* __restrict__ Wd2,
                         unsigned short* __restrict__ WT1, unsigned short* __restrict__ WT2,
                         unsigned short* __restrict__ WdT1, unsigned short* __restrict__ WdT2) {
    int id = blockIdx.x * blockDim.x + threadIdx.x;
    if (id < 32768) {
        int k = id & 255, n = id >> 8;
        float v = (k < 128) ? Ws1[k * 128 + n] : Wn1[(k - 128) * 128 + n];
        WT1[n * 256 + k] = f2b(v);
    } else if (id < 65536) {
        int r = id - 32768; int k = r & 255, n = r >> 8;
        float v = (k < 128) ? Ws2[k * 128 + n] : Wn2[(k - 128) * 128 + n];
        WT2[n * 256 + k] = f2b(v);
    } else if (id < 81920) {
        int r = id - 65536; int k = r & 127, n = r >> 7;
        WdT1[n * 128 + k] = f2b(Wd1[k * 128 + n]);
    } else if (id < 98304) {
        int r = id - 81920; int k = r & 127, n = r >> 7;
        WdT2[n * 128 + k] = f2b(Wd2[k * 128 + n]);
    }
}

// ---- CSR build ----
__global__ void k_deg(const int* __restrict__ dst, int* __restrict__ deg) {
    int e = blockIdx.x * blockDim.x + threadIdx.x;
    if (e < N_EDGES) atomicAdd(&deg[dst[e]], 1);
}

__global__ void k_scan1(const int* __restrict__ deg, int* __restrict__ row_ptr,
                        int* __restrict__ bsum, int n) {
    __shared__ int tmp[1024];
    int i = blockIdx.x * 1024 + threadIdx.x;
    int d = (i < n) ? deg[i] : 0;
    tmp[threadIdx.x] = d;
    __syncthreads();
    int run = d;
    for (int off = 1; off < 1024; off <<= 1) {
        int t = (threadIdx.x >= off) ? tmp[threadIdx.x - off] : 0;
        __syncthreads();
        run += t;
        tmp[threadIdx.x] = run;
        __syncthreads();
    }
    if (i < n) row_ptr[i] = run - d;       // block-local exclusive
    if (threadIdx.x == 1023) bsum[blockIdx.x] = run;
}

__global__ void k_scan2(int* __restrict__ bsum, int nb) {
    if (blockIdx.x == 0 && threadIdx.x == 0) {
        int acc = 0;
        for (int b = 0; b < nb; b++) { int t = bsum[b]; bsum[b] = acc; acc += t; }
    }
}

__global__ void k_add(int* __restrict__ row_ptr, int* __restrict__ cursor,
                      const int* __restrict__ bsum, int n) {
    int i = blockIdx.x * 1024 + threadIdx.x;
    if (i < n) {
        int v = row_ptr[i] + bsum[blockIdx.x];
        row_ptr[i] = v;
        cursor[i] = v;
    }
    if (i == 0) row_ptr[n] = N_EDGES;
}

__global__ void k_scatter(const int* __restrict__ src, const int* __restrict__ dst,
                          int* __restrict__ cursor, int* __restrict__ colA) {
    int e = blockIdx.x * blockDim.x + threadIdx.x;
    if (e < N_EDGES) {
        int d = dst[e];
        int slot = atomicAdd(&cursor[d], 1);
        colA[slot] = src[e];
    }
}

// ---- mean aggregation: one wave per dst node, lane handles 2 features ----
template <bool BF16IN>
__global__ __launch_bounds__(256) void k_agg(const float* __restrict__ xf,
                                             const unsigned short* __restrict__ hb, int ldh,
                                             const int* __restrict__ row_ptr,
                                             const int* __restrict__ colA,
                                             unsigned short* __restrict__ outm, int ldo) {
    int w = (blockIdx.x * blockDim.x + threadIdx.x) >> 6;
    int lane = threadIdx.x & 63;
    if (w >= N_NODES) return;
    int s = row_ptr[w], e = row_ptr[w + 1];
    float a0 = 0.f, a1 = 0.f;
    for (int base = s; base < e; base += 64) {
        int ce = (base + lane < e) ? colA[base + lane] : 0;
        int cnt = min(64, e - base);
        int i = 0;
        for (; i + 1 < cnt; i += 2) {
            int s0 = __shfl(ce, i, 64);
            int s1 = __shfl(ce, i + 1, 64);
            if (BF16IN) {
                unsigned v0 = *(const unsigned*)(hb + s0 * ldh + 2 * lane);
                unsigned v1 = *(const unsigned*)(hb + s1 * ldh + 2 * lane);
                a0 += b2f(v0 & 0xffff) + b2f(v1 & 0xffff);
                a1 += b2f(v0 >> 16) + b2f(v1 >> 16);
            } else {
                float2 v0 = *(const float2*)(xf + s0 * 128 + 2 * lane);
                float2 v1 = *(const float2*)(xf + s1 * 128 + 2 * lane);
                a0 += v0.x + v1.x;
                a1 += v0.y + v1.y;
            }
        }
        if (i < cnt) {
            int s0 = __shfl(ce, i, 64);
            if (BF16IN) {
                unsigned v0 = *(const unsigned*)(hb + s0 * ldh + 2 * lane);
                a0 += b2f(v0 & 0xffff);
                a1 += b2f(v0 >> 16);
            } else {
                float2 v0 = *(const float2*)(xf + s0 * 128 + 2 * lane);
                a0 += v0.x;
                a1 += v0.y;
            }
        }
    }
    float rd = 1.0f / (float)max(e - s, 1);
    unsigned o = (unsigned)f2b(a0 * rd) | ((unsigned)f2b(a1 * rd) << 16);
    *(unsigned*)(outm + w * ldo + 2 * lane) = o;
}

// ---- fused SAGE layer GEMM: H = act(A[M,K] @ W[K,128] + b), W given as BT[128][K] bf16 ----
__global__ __launch_bounds__(256) void k_gemm(const unsigned short* __restrict__ A, int lda, int K,
                                              const unsigned short* __restrict__ BT,
                                              const float* __restrict__ bias,
                                              unsigned short* __restrict__ Hout, int ldo,
                                              int M, int relu) {
    int wv = threadIdx.x >> 6, lane = threadIdx.x & 63;
    int lr = lane & 15, lq = lane >> 4;
    int r0 = blockIdx.x * 64 + wv * 16;
    int arow = r0 + lr;
    if (arow > M - 1) arow = M - 1;
    f32x4 acc[8];
    f32x4 zero = {0.f, 0.f, 0.f, 0.f};
#pragma unroll
    for (int ct = 0; ct < 8; ct++) acc[ct] = zero;
    for (int kb = 0; kb < K; kb += 32) {
        int ka = kb + lq * 8;
        bf16x8 af = *(const bf16x8*)(A + arow * lda + ka);
#pragma unroll
        for (int ct = 0; ct < 8; ct++) {
            bf16x8 bf = *(const bf16x8*)(BT + (ct * 16 + lr) * K + ka);
            acc[ct] = __builtin_amdgcn_mfma_f32_16x16x32_bf16(af, bf, acc[ct], 0, 0, 0);
        }
    }
#pragma unroll
    for (int ct = 0; ct < 8; ct++) {
        int colc = ct * 16 + lr;
        float bv = bias[colc];
#pragma unroll
        for (int r = 0; r < 4; r++) {
            int row = r0 + lq * 4 + r;
            if (row < M) {
                float v = acc[ct][r] + bv;
                if (relu) v = fmaxf(v, 0.f);
                Hout[row * ldo + colc] = f2b(v);
            }
        }
    }
}

// ---- fused edge decoder: per 64-pair tile, z -> MLP(128->128->128->1) ----
__global__ __launch_bounds__(256) void k_decode(const unsigned short* __restrict__ h2b,
                                                const int* __restrict__ psrc,
                                                const int* __restrict__ pdst,
                                                const unsigned short* __restrict__ WdT1,
                                                const unsigned short* __restrict__ WdT2,
                                                const float* __restrict__ bd1,
                                                const float* __restrict__ bd2,
                                                const float* __restrict__ Wd3,
                                                const float* __restrict__ bd3,
                                                float* __restrict__ out, int P) {
    __shared__ unsigned short zt[64][136];
    __shared__ unsigned short t1[64][136];
    const int tid = threadIdx.x;
    const int tile0 = blockIdx.x * 64;
    {
        int pp = tid >> 2, c = tid & 3;
        int g = tile0 + pp;
        int gc = (g < P) ? g : (P - 1);
        int s = psrc[gc], d = pdst[gc];
        const unsigned short* rs = h2b + s * 128;
        const unsigned short* rd = h2b + d * 128;
#pragma unroll
        for (int v = 0; v < 4; v++) {
            int f = c * 32 + v * 8;
            uint4 av = *(const uint4*)(rs + f);
            uint4 bv = *(const uint4*)(rd + f);
            uint4 res;
            unsigned* rp = (unsigned*)&res;
            const unsigned* ap = (const unsigned*)&av;
            const unsigned* bp = (const unsigned*)&bv;
#pragma unroll
            for (int j = 0; j < 4; j++) {
                unsigned short lo = f2b(b2f(ap[j] & 0xffff) * b2f(bp[j] & 0xffff));
                unsigned short hi = f2b(b2f(ap[j] >> 16) * b2f(bp[j] >> 16));
                rp[j] = (unsigned)lo | ((unsigned)hi << 16);
            }
            *(uint4*)(&zt[pp][f]) = res;
        }
    }
    __syncthreads();
    const int wv = tid >> 6, lane = tid & 63, lr = lane & 15, lq = lane >> 4;
    f32x4 zero = {0.f, 0.f, 0.f, 0.f};
    f32x4 acc[8];
#pragma unroll
    for (int ct = 0; ct < 8; ct++) acc[ct] = zero;
#pragma unroll
    for (int kb = 0; kb < 128; kb += 32) {
        int ka = kb + lq * 8;
        bf16x8 af = *(const bf16x8*)(&zt[wv * 16 + lr][ka]);
#pragma unroll
        for (int ct = 0; ct < 8; ct++) {
            bf16x8 bf = *(const bf16x8*)(WdT1 + (ct * 16 + lr) * 128 + ka);
            acc[ct] = __builtin_amdgcn_mfma_f32_16x16x32_bf16(af, bf, acc[ct], 0, 0, 0);
        }
    }
#pragma unroll
    for (int ct = 0; ct < 8; ct++) {
        int colc = ct * 16 + lr;
        float bv = bd1[colc];
#pragma unroll
        for (int r = 0; r < 4; r++) {
            float v = fmaxf(acc[ct][r] + bv, 0.f);
            t1[wv * 16 + lq * 4 + r][colc] = f2b(v);
        }
    }
    __syncthreads();
#pragma unroll
    for (int ct = 0; ct < 8; ct++) acc[ct] = zero;
#pragma unroll
    for (int kb = 0; kb < 128; kb += 32) {
        int ka = kb + lq * 8;
        bf16x8 af = *(const bf16x8*)(&t1[wv * 16 + lr][ka]);
#pragma unroll
        for (int ct = 0; ct < 8; ct++) {
            bf16x8 bf = *(const bf16x8*)(WdT2 + (ct * 16 + lr) * 128 + ka);
            acc[ct] = __builtin_amdgcn_mfma_f32_16x16x32_bf16(af, bf, acc[ct], 0, 0, 0);
        }
    }
    float sc[4] = {0.f, 0.f, 0.f, 0.f};
#pragma unroll
    for (int ct = 0; ct < 8; ct++) {
        int colc = ct * 16 + lr;
        float bv = bd2[colc];
        float w3 = Wd3[colc];
#pragma unroll
        for (int r = 0; r < 4; r++) {
            float v = fmaxf(acc[ct][r] + bv, 0.f);
            sc[r] += v * w3;
        }
    }
#pragma unroll
    for (int m = 1; m < 16; m <<= 1) {
#pragma unroll
        for (int r = 0; r < 4; r++) sc[r] += __shfl_xor(sc[r], m, 64);
    }
    if (lr == 0) {
        float b3 = bd3[0];
#pragma unroll
        for (int r = 0; r < 4; r++) {
            int g = tile0 + wv * 16 + lq * 4 + r;
            if (g < P) out[g] = sc[r] + b3;
        }
    }
}

static inline size_t alignup(size_t v) { return (v + 255) & ~(size_t)255; }

extern "C" void kernel_launch(void* const* d_in, const int* in_sizes, int n_in,
                              void* d_out, int out_size, void* d_ws, size_t ws_size,
                              hipStream_t stream) {
    const float* x = (const float*)d_in[0];
    const int* edge_src = (const int*)d_in[1];
    const int* edge_dst = (const int*)d_in[2];
    const int* pos_src = (const int*)d_in[3];
    const int* pos_dst = (const int*)d_in[4];
    const int* neg_src = (const int*)d_in[5];
    const int* neg_dst = (const int*)d_in[6];
    const float* Ws1 = (const float*)d_in[7];
    const float* Wn1 = (const float*)d_in[8];
    const float* b1 = (const float*)d_in[9];
    const float* Ws2 = (const float*)d_in[10];
    const float* Wn2 = (const float*)d_in[11];
    const float* b2 = (const float*)d_in[12];
    const float* Wd1 = (const float*)d_in[13];
    const float* bd1 = (const float*)d_in[14];
    const float* Wd2 = (const float*)d_in[15];
    const float* bd2 = (const float*)d_in[16];
    const float* Wd3 = (const float*)d_in[17];
    const float* bd3 = (const float*)d_in[18];
    float* out = (float*)d_out;

    char* p = (char*)d_ws;
    int* deg = (int*)p;            p += alignup(N_NODES * 4);
    int* row_ptr = (int*)p;        p += alignup((N_NODES + 1) * 4);
    int* cursor = (int*)p;         p += alignup(N_NODES * 4);
    int* bsum = (int*)p;           p += alignup(64 * 4);
    int* colA = (int*)p;           p += alignup(N_EDGES * 4);
    unsigned short* A1 = (unsigned short*)p;  p += alignup((size_t)N_NODES * 256 * 2);
    unsigned short* A2 = (unsigned short*)p;  p += alignup((size_t)N_NODES * 256 * 2);
    unsigned short* h2b = (unsigned short*)p; p += alignup((size_t)N_NODES * 128 * 2);
    unsigned short* WT1 = (unsigned short*)p;  p += alignup(32768 * 2);
    unsigned short* WT2 = (unsigned short*)p;  p += alignup(32768 * 2);
    unsigned short* WdT1 = (unsigned short*)p; p += alignup(16384 * 2);
    unsigned short* WdT2 = (unsigned short*)p; p += alignup(16384 * 2);

    hipMemsetAsync(deg, 0, N_NODES * 4, stream);

    k_convert_x<<<(N_NODES * 32 + 255) / 256, 256, 0, stream>>>(x, A1);
    k_prep_w<<<384, 256, 0, stream>>>(Ws1, Wn1, Ws2, Wn2, Wd1, Wd2, WT1, WT2, WdT1, WdT2);

    k_deg<<<(N_EDGES + 255) / 256, 256, 0, stream>>>(edge_dst, deg);
    int nb1 = (N_NODES + 1023) / 1024;
    k_scan1<<<nb1, 1024, 0, stream>>>(deg, row_ptr, bsum, N_NODES);
    k_scan2<<<1, 1, 0, stream>>>(bsum, nb1);
    k_add<<<nb1, 1024, 0, stream>>>(row_ptr, cursor, bsum, N_NODES);
    k_scatter<<<(N_EDGES + 255) / 256, 256, 0, stream>>>(edge_src, edge_dst, cursor, colA);

    // layer 1: mean(x) -> A1[:,128:], then H1 = relu([x,mean] @ [Ws1;Wn1] + b1) -> A2[:,0:128]
    k_agg<false><<<(N_NODES + 3) / 4, 256, 0, stream>>>(x, nullptr, 0, row_ptr, colA, A1 + 128, 256);
    k_gemm<<<(N_NODES + 63) / 64, 256, 0, stream>>>(A1, 256, 256, WT1, b1, A2, 256, N_NODES, 1);

    // layer 2: mean(h1) -> A2[:,128:], then H2 = [h1,mean] @ [Ws2;Wn2] + b2 -> h2b
    k_agg<true><<<(N_NODES + 3) / 4, 256, 0, stream>>>(nullptr, A2, 256, row_ptr, colA, A2 + 128, 256);
    k_gemm<<<(N_NODES + 63) / 64, 256, 0, stream>>>(A2, 256, 256, WT2, b2, h2b, 128, N_NODES, 0);

    // decoder: pos then neg
    int ndb = (N_PAIRS + 63) / 64;
    k_decode<<<ndb, 256, 0, stream>>>(h2b, pos_src, pos_dst, WdT1, WdT2, bd1, bd2, Wd3, bd3, out, N_PAIRS);
    k_decode<<<ndb, 256, 0, stream>>>(h2b, neg_src, neg_dst, WdT1, WdT2, bd1, bd2, Wd3, bd3, out + N_PAIRS, N_PAIRS);
}